// Round 9
// baseline (560.684 us; speedup 1.0000x reference)
//
#include <hip/hip_runtime.h>

// GraphAttentionLayer: B=16, M=2048, F_IN=128, F_OUT=64, ALPHA=0.2
// out = elu( softmax_j( mask(adj, leaky_relu(f1_i + f2_j)) ) @ (h@W) )
//
// Dtypes per the documented contract: h/W/a = float32, adj = int32,
// OUTPUT = float32 (reference returns fp32; "bf16" in the test label is
// hardcoded template text). Zero d_ws use (ws_size was never validated —
// the R1/R4/R5 garbage). Fully fused, one kernel, no cross-kernel state.
//
// Algebra: h' = ((P @ h) @ W)/den with P = masked exp(leaky_relu(f1_i+f2_j)),
// f1 = h@(W@a1), f2 = h@(W@a2) — nothing materialized to global.
// P and h-tiles in bf16 for MFMA 16x16x32; denom from the ROUNDED p for
// consistency between numerator and denominator.

#define M_     2048
#define FIN_   128
#define F_     64
#define ALPHA_ 0.2f
#define ROWS_  32
#define PAD_   36          // hT inner stride in u16: 72B rows, odd dword stride

typedef float  float4_ __attribute__((ext_vector_type(4)));
typedef short  short4_ __attribute__((ext_vector_type(4)));
typedef short  short8  __attribute__((ext_vector_type(8)));
typedef int    int4_   __attribute__((ext_vector_type(4)));
typedef unsigned short u16;

static __device__ __forceinline__ float bf2f(u16 u) {
    return __uint_as_float(((unsigned)u) << 16);
}
static __device__ __forceinline__ u16 f2bf(float f) {
    unsigned u = __float_as_uint(f);
    unsigned r = u + 0x7FFFu + ((u >> 16) & 1u);
    return (u16)(r >> 16);
}

__global__ __launch_bounds__(256, 2) void k_gat(
    const float* __restrict__ h, const int* __restrict__ adj,
    const float* __restrict__ W, const float* __restrict__ a,
    float* __restrict__ out)
{
    __shared__ u16   Wl[FIN_ * F_];          // 16 KB   W bf16, [k*64+n]
    __shared__ float a_s[2 * F_];            // 512 B
    __shared__ float wa1[FIN_], wa2[FIN_];   // 1 KB    W@a1, W@a2
    __shared__ float f1s[ROWS_];
    __shared__ float f2s[M_];                // 8 KB
    __shared__ u16   hT[4][FIN_ * PAD_];     // 36 KB   per-wave transposed h tile
    __shared__ float Tsum[ROWS_][FIN_ + 1];  // 16.5 KB (P@h accumulator)
    __shared__ float dens4[4][ROWS_];        // 512 B

    const int tid  = threadIdx.x;
    const int w    = tid >> 6;
    const int l    = tid & 63;
    const int lc   = l & 15;
    const int quad = l >> 4;
    const int b    = blockIdx.x >> 6;
    const int i0   = (blockIdx.x & 63) * ROWS_;

    // ---------------- stage a, W (bf16); zero Tsum ---------------------------
    if (tid < 128) a_s[tid] = a[tid];
    for (int e = tid; e < FIN_ * F_; e += 256) Wl[e] = f2bf(W[e]);
    {
        float* tz = &Tsum[0][0];
        for (int e = tid; e < ROWS_ * (FIN_ + 1); e += 256) tz[e] = 0.f;
    }
    __syncthreads();

    // ---------------- wa1/wa2 = W @ a1, W @ a2 (fp32 W reload, tiny) ---------
    if (tid < FIN_) {
        float s1 = 0.f, s2 = 0.f;
#pragma unroll 8
        for (int n = 0; n < F_; ++n) {
            float wv = W[tid * F_ + n];
            s1 += wv * a_s[n];
            s2 += wv * a_s[F_ + n];
        }
        wa1[tid] = s1;
        wa2[tid] = s2;
    }
    __syncthreads();

    // ---------------- f1 for this block's 32 rows ----------------------------
    {
        const int i = tid >> 3, sub = tid & 7, k0 = sub * 16;
        const float* hp = h + ((size_t)(b * M_ + i0 + i)) * FIN_ + k0;
        float s = 0.f;
#pragma unroll
        for (int k = 0; k < 16; ++k) s += hp[k] * wa1[k0 + k];
        s += __shfl_xor(s, 1, 64);
        s += __shfl_xor(s, 2, 64);
        s += __shfl_xor(s, 4, 64);
        if (sub == 0) f1s[i] = s;
    }
    __syncthreads();

    // ---------------- main loop: T[32][128] += P[32][32j] * h[32j][128] ------
    float4_ acc[2][8];
#pragma unroll
    for (int mt = 0; mt < 2; ++mt)
#pragma unroll
        for (int nt = 0; nt < 8; ++nt) acc[mt][nt] = (float4_){0.f, 0.f, 0.f, 0.f};
    float dsum0 = 0.f, dsum1 = 0.f;
    u16* myT = hT[w];
    const int jl  = l & 31;          // staging: j within tile
    const int kh0 = (l >> 5) * 64;   // staging: k half

    for (int jt = w; jt < 64; jt += 4) {
        const int j0 = jt * 32;

        // stage 32j x 128k transposed h tile (wave-private) + f2 partials
        {
            const float* hp = h + ((size_t)(b * M_ + j0 + jl)) * FIN_ + kh0;
            float fpart = 0.f;
#pragma unroll
            for (int c = 0; c < 16; ++c) {
                float4_ v = *(const float4_*)(hp + c * 4);
#pragma unroll
                for (int kk = 0; kk < 4; ++kk) {
                    float x = v[kk];
                    myT[(kh0 + c * 4 + kk) * PAD_ + jl] = f2bf(x);
                    fpart += x * wa2[kh0 + c * 4 + kk];
                }
            }
            fpart += __shfl_xor(fpart, 32, 64);
            if (l < 32) f2s[j0 + jl] = fpart;
        }
        __syncthreads();

        // scores -> A fragments (P bf16); denom from the ROUNDED p
        short8 af[2];
#pragma unroll
        for (int mt = 0; mt < 2; ++mt) {
            const float f1r = f1s[mt * 16 + lc];
            const int*  ap  = adj + ((size_t)(b * M_ + i0 + mt * 16 + lc)) * M_ + j0 + quad * 8;
            int4_ c0 = *(const int4_*)ap;
            int4_ c1 = *(const int4_*)(ap + 4);
            const float* fb = &f2s[j0 + quad * 8];
            float d = 0.f;
            short8 a8;
#define GAT_SC(jj, ai)                                                  \
            {                                                           \
                float x_ = f1r + fb[jj];                                \
                x_ = fmaxf(x_, ALPHA_ * x_);                            \
                x_ = fminf(fmaxf(x_, -30.f), 30.f);                     \
                float e_ = ((ai) > 0) ? __expf(x_) : 0.f;               \
                u16 pb_ = f2bf(e_);                                     \
                a8[jj] = (short)pb_;                                    \
                d += bf2f(pb_);                                         \
            }
            GAT_SC(0, c0[0]) GAT_SC(1, c0[1]) GAT_SC(2, c0[2]) GAT_SC(3, c0[3])
            GAT_SC(4, c1[0]) GAT_SC(5, c1[1]) GAT_SC(6, c1[2]) GAT_SC(7, c1[3])
#undef GAT_SC
            af[mt] = a8;
            if (mt == 0) dsum0 += d; else dsum1 += d;
        }

        // MFMA: acc[mt][nt] += P * hT   (A[m=lc][k=quad*8+j], B[n=lc][k=quad*8+j])
#pragma unroll
        for (int nt = 0; nt < 8; ++nt) {
            const u16* bp = myT + (nt * 16 + lc) * PAD_ + quad * 8;
            short4_ b0 = *(const short4_*)bp;
            short4_ b1 = *(const short4_*)(bp + 4);
            short8 bf;
            bf[0] = b0[0]; bf[1] = b0[1]; bf[2] = b0[2]; bf[3] = b0[3];
            bf[4] = b1[0]; bf[5] = b1[1]; bf[6] = b1[2]; bf[7] = b1[3];
            acc[0][nt] = __builtin_amdgcn_mfma_f32_16x16x32_bf16(af[0], bf, acc[0][nt], 0, 0, 0);
            acc[1][nt] = __builtin_amdgcn_mfma_f32_16x16x32_bf16(af[1], bf, acc[1][nt], 0, 0, 0);
        }
    }

    // ---------------- reduce: denom + T across waves -------------------------
    dsum0 += __shfl_xor(dsum0, 16, 64);
    dsum0 += __shfl_xor(dsum0, 32, 64);
    dsum1 += __shfl_xor(dsum1, 16, 64);
    dsum1 += __shfl_xor(dsum1, 32, 64);
    if (l < 16) { dens4[w][l] = dsum0; dens4[w][16 + l] = dsum1; }

    // C/D layout: row = quad*4 + mm, col = nt*16 + lc
#pragma unroll
    for (int mt = 0; mt < 2; ++mt)
#pragma unroll
        for (int nt = 0; nt < 8; ++nt)
#pragma unroll
            for (int mm = 0; mm < 4; ++mm)
                atomicAdd(&Tsum[mt * 16 + quad * 4 + mm][nt * 16 + lc], acc[mt][nt][mm]);
    __syncthreads();

    // ---------------- epilogue: out = elu( (T @ W) / den ), fp32 stores ------
    {
        const int i  = tid >> 3;
        const int n0 = (tid & 7) * 8;
        const float den = dens4[0][i] + dens4[1][i] + dens4[2][i] + dens4[3][i];
        const float rden = (den > 0.f) ? (1.f / den) : 0.f;
        float u[8];
#pragma unroll
        for (int nn = 0; nn < 8; ++nn) u[nn] = 0.f;
        for (int k = 0; k < FIN_; ++k) {
            const float tv = Tsum[i][k];
            const u16* wp = &Wl[k * F_ + n0];
#pragma unroll
            for (int nn = 0; nn < 8; ++nn) u[nn] += tv * bf2f(wp[nn]);
        }
        float4_ o0, o1;
#pragma unroll
        for (int nn = 0; nn < 8; ++nn) {
            float hp = u[nn] * rden;
            float o  = hp > 0.f ? hp : expm1f(hp);
            if (nn < 4) o0[nn] = o; else o1[nn - 4] = o;
        }
        float* op = out + ((size_t)(b * M_ + i0 + i)) * F_ + n0;
        *(float4_*)op       = o0;
        *(float4_*)(op + 4) = o1;
    }
}

// ---------------------------------------------------------------------------
extern "C" void kernel_launch(void* const* d_in, const int* in_sizes, int n_in,
                              void* d_out, int out_size, void* d_ws, size_t ws_size,
                              hipStream_t stream)
{
    (void)out_size; (void)d_ws; (void)ws_size;
    // Inputs in dict order (documented); size-based resolution as insurance.
    const float* h  = (const float*)d_in[0];
    const int* adjp = (const int*)d_in[1];
    const float* Wp = (const float*)d_in[2];
    const float* ap = (const float*)d_in[3];
    for (int i = 0; i < n_in; ++i) {
        long s = in_sizes[i];
        if      (s == 4194304L)  h    = (const float*)d_in[i];
        else if (s == 67108864L) adjp = (const int*)d_in[i];
        else if (s == 8192L)     Wp   = (const float*)d_in[i];
        else if (s == 128L)      ap   = (const float*)d_in[i];
    }

    k_gat<<<1024, 256, 0, stream>>>(h, adjp, Wp, ap, (float*)d_out);
}

// Round 11
// 433.457 us; speedup vs baseline: 1.2935x; 1.2935x over previous
//
#include <hip/hip_runtime.h>

// GraphAttentionLayer: B=16, M=2048, F_IN=128, F_OUT=64, ALPHA=0.2
// out = elu( softmax_j( mask(adj, leaky_relu(f1_i + f2_j)) ) @ (h@W) )
// Dtypes (verified R9): h/W/a fp32, adj int32, out fp32.
//
// Single fused kernel, zero d_ws (cross-kernel ws handoff failed in R4/R5/R10).
// Algebra: h' = ((P @ h) @ W)/den, f1 = h@(W@a1), f2 = h@(W@a2).
// Per block: 32 q-rows. Loop over 64 tiles of 32 j-tokens:
//   prefetch adj -> stage shared hT[feat][token] bf16 + f2 tile -> P (scores)
//   once into LDS (A-frag layout) -> 4 waves MFMA disjoint (mt,nt) slices.
// LDS ~35 KB -> 4 blocks/CU (vs R9's 78.5 KB -> 2).

#define M_     2048
#define FIN_   128
#define F_     64
#define ALPHA_ 0.2f
#define ROWS_  32
#define TS_    36      // hT/P token stride in u16 (72 B rows: 8B-aligned, odd dword)
#define WT_    132     // Tsum row stride in floats

typedef float  float4_ __attribute__((ext_vector_type(4)));
typedef short  short4_ __attribute__((ext_vector_type(4)));
typedef short  short8  __attribute__((ext_vector_type(8)));
typedef int    int4_   __attribute__((ext_vector_type(4)));
typedef unsigned short u16;
typedef unsigned int   u32;

static __device__ __forceinline__ float bf2f(u16 u) {
    return __uint_as_float(((u32)u) << 16);
}
static __device__ __forceinline__ u16 f2bf(float f) {
    u32 u = __float_as_uint(f);
    u32 r = u + 0x7FFFu + ((u >> 16) & 1u);
    return (u16)(r >> 16);
}

__global__ __launch_bounds__(256, 4) void k_gat2(
    const float* __restrict__ h, const int* __restrict__ adj,
    const float* __restrict__ W, const float* __restrict__ a,
    float* __restrict__ out)
{
    __shared__ u16   Wl[FIN_ * F_];          // 16 KB   W bf16 [k*64+n] (epilogue)
    __shared__ float a_s[2 * F_];            // 512 B
    __shared__ float wa1[FIN_], wa2[FIN_];   // 1 KB
    __shared__ float f1s[ROWS_];
    __shared__ float dens[ROWS_];
    __shared__ char  dyn[32 * WT_ * 4];      // 16896 B: loop buffers / Tsum (aliased)

    u16*   hT   = (u16*)dyn;                 // [128][TS_]  9216 B  h-tile, [feat][token]
    u16*   P    = (u16*)(dyn + 9216);        // [32][TS_]   2304 B  scores bf16
    float* f2t  = (float*)(dyn + 11520);     // [32]        128 B   f2 for this tile
    float* Tsum = (float*)dyn;               // [32][WT_]   16896 B (epilogue only)

    const int tid  = threadIdx.x;
    const int w    = tid >> 6;
    const int l    = tid & 63;
    const int lc   = l & 15;
    const int quad = l >> 4;
    const int b    = blockIdx.x >> 6;
    const int i0   = (blockIdx.x & 63) * ROWS_;

    // ---------------- stage a, W (bf16) --------------------------------------
    if (tid < 128) a_s[tid] = a[tid];
    for (int e = tid; e < FIN_ * F_; e += 256) Wl[e] = f2bf(W[e]);
    __syncthreads();

    // ---------------- wa1/wa2 = W @ a1, W @ a2 (fp32) ------------------------
    if (tid < FIN_) {
        float s1 = 0.f, s2 = 0.f;
#pragma unroll 8
        for (int n = 0; n < F_; ++n) {
            float wv = W[tid * F_ + n];
            s1 += wv * a_s[n];
            s2 += wv * a_s[F_ + n];
        }
        wa1[tid] = s1;
        wa2[tid] = s2;
    }
    __syncthreads();

    // ---------------- f1 for this block's 32 rows ----------------------------
    {
        const int i = tid >> 3, sub = tid & 7, k0 = sub * 16;
        const float* hp = h + ((size_t)(b * M_ + i0 + i)) * FIN_ + k0;
        float s = 0.f;
#pragma unroll
        for (int k = 0; k < 16; ++k) s += hp[k] * wa1[k0 + k];
        s += __shfl_xor(s, 1, 64);
        s += __shfl_xor(s, 2, 64);
        s += __shfl_xor(s, 4, 64);
        if (sub == 0) f1s[i] = s;
    }
    __syncthreads();

    // per-thread fixed roles
    const int prow = tid >> 3;           // P phase: q-row 0..31
    const int ps   = tid & 7;            // P phase: token slice (4 tokens)
    const int sf0  = (tid & 15) * 8;     // staging: feature octet
    const int stp  = (tid >> 4) * 2;     // staging: token pair
    const int mt   = w & 1;              // MFMA: row half (16 rows)
    const int ntb  = (w >> 1) * 4;       // MFMA: 4 of 8 nt slices
    const float f1r = f1s[prow];
    float denacc = 0.f;

    float4_ acc[4];
#pragma unroll
    for (int c = 0; c < 4; ++c) acc[c] = (float4_){0.f, 0.f, 0.f, 0.f};

    const int*   aprow = adj + ((size_t)(b * M_ + i0 + prow)) * M_ + ps * 4;
    const float* hbase = h + ((size_t)(b * M_ + stp)) * FIN_ + sf0;

    for (int it = 0; it < 64; ++it) {
        const int j0 = it * 32;

        // prefetch this tile's adj (independent of LDS staging below)
        int4_ c4 = *(const int4_*)(aprow + j0);

        // ---- stage hT (bf16, [feat][token]) + f2 tile ----
        {
            const float* hp0 = hbase + (size_t)j0 * FIN_;
            const float* hp1 = hp0 + FIN_;
            float4_ x0 = *(const float4_*)hp0, x1 = *(const float4_*)(hp0 + 4);
            float4_ y0 = *(const float4_*)hp1, y1 = *(const float4_*)(hp1 + 4);
            float xa[8] = {x0[0], x0[1], x0[2], x0[3], x1[0], x1[1], x1[2], x1[3]};
            float ya[8] = {y0[0], y0[1], y0[2], y0[3], y1[0], y1[1], y1[2], y1[3]};
            float fp0 = 0.f, fp1 = 0.f;
#pragma unroll
            for (int kk = 0; kk < 8; ++kk) {
                const int k = sf0 + kk;
                u16 u0 = f2bf(xa[kk]), u1 = f2bf(ya[kk]);
                *(u32*)(hT + k * TS_ + stp) = (u32)u0 | ((u32)u1 << 16);
                fp0 += xa[kk] * wa2[k];
                fp1 += ya[kk] * wa2[k];
            }
            fp0 += __shfl_xor(fp0, 1, 64); fp1 += __shfl_xor(fp1, 1, 64);
            fp0 += __shfl_xor(fp0, 2, 64); fp1 += __shfl_xor(fp1, 2, 64);
            fp0 += __shfl_xor(fp0, 4, 64); fp1 += __shfl_xor(fp1, 4, 64);
            fp0 += __shfl_xor(fp0, 8, 64); fp1 += __shfl_xor(fp1, 8, 64);
            if ((tid & 15) == 0) { f2t[stp] = fp0; f2t[stp + 1] = fp1; }
        }
        __syncthreads();

        // ---- P: scores -> LDS (A-frag layout), denom from ROUNDED p ----
        {
            float4_ g = *(const float4_*)(f2t + ps * 4);
            u32 pk0, pk1;
            float d = 0.f;
            {
                float x_ = f1r + g[0]; x_ = fmaxf(x_, ALPHA_ * x_);
                float e_ = (c4[0] > 0) ? __expf(x_) : 0.f;
                u16 pb = f2bf(e_); d += bf2f(pb); pk0 = (u32)pb;
            }
            {
                float x_ = f1r + g[1]; x_ = fmaxf(x_, ALPHA_ * x_);
                float e_ = (c4[1] > 0) ? __expf(x_) : 0.f;
                u16 pb = f2bf(e_); d += bf2f(pb); pk0 |= ((u32)pb << 16);
            }
            {
                float x_ = f1r + g[2]; x_ = fmaxf(x_, ALPHA_ * x_);
                float e_ = (c4[2] > 0) ? __expf(x_) : 0.f;
                u16 pb = f2bf(e_); d += bf2f(pb); pk1 = (u32)pb;
            }
            {
                float x_ = f1r + g[3]; x_ = fmaxf(x_, ALPHA_ * x_);
                float e_ = (c4[3] > 0) ? __expf(x_) : 0.f;
                u16 pb = f2bf(e_); d += bf2f(pb); pk1 |= ((u32)pb << 16);
            }
            *(u32*)(P + prow * TS_ + ps * 4)     = pk0;
            *(u32*)(P + prow * TS_ + ps * 4 + 2) = pk1;
            denacc += d;
        }
        __syncthreads();

        // ---- MFMA: wave (mt, ntb..ntb+3); A from P, B from hT ----
        {
            const u16* apx = P + (mt * 16 + lc) * TS_ + quad * 8;
            short4_ a0 = *(const short4_*)apx;
            short4_ a1 = *(const short4_*)(apx + 4);
            short8 af;
            af[0] = a0[0]; af[1] = a0[1]; af[2] = a0[2]; af[3] = a0[3];
            af[4] = a1[0]; af[5] = a1[1]; af[6] = a1[2]; af[7] = a1[3];
#pragma unroll
            for (int c = 0; c < 4; ++c) {
                const u16* bp = hT + ((ntb + c) * 16 + lc) * TS_ + quad * 8;
                short4_ b0 = *(const short4_*)bp;
                short4_ b1 = *(const short4_*)(bp + 4);
                short8 bf;
                bf[0] = b0[0]; bf[1] = b0[1]; bf[2] = b0[2]; bf[3] = b0[3];
                bf[4] = b1[0]; bf[5] = b1[1]; bf[6] = b1[2]; bf[7] = b1[3];
                acc[c] = __builtin_amdgcn_mfma_f32_16x16x32_bf16(af, bf, acc[c], 0, 0, 0);
            }
        }
        __syncthreads();   // protect hT/P before next stage (and Tsum alias after loop)
    }

    // ---------------- denom: reduce 8 threads per row ------------------------
    denacc += __shfl_xor(denacc, 1, 64);
    denacc += __shfl_xor(denacc, 2, 64);
    denacc += __shfl_xor(denacc, 4, 64);
    if (ps == 0) dens[prow] = denacc;

    // ---------------- T -> LDS (disjoint per wave, no atomics) ---------------
    // C/D: row = quad*4+mm (within mt half), col = (ntb+c)*16+lc
#pragma unroll
    for (int c = 0; c < 4; ++c)
#pragma unroll
        for (int mm = 0; mm < 4; ++mm)
            Tsum[(mt * 16 + quad * 4 + mm) * WT_ + (ntb + c) * 16 + lc] = acc[c][mm];
    __syncthreads();

    // ---------------- epilogue: out = elu( (T @ W) / den ) -------------------
    {
        const int row = tid >> 3;
        const int n0  = (tid & 7) * 8;
        const float den  = dens[row];
        const float rden = (den > 0.f) ? (1.f / den) : 0.f;
        float u[8];
#pragma unroll
        for (int nn = 0; nn < 8; ++nn) u[nn] = 0.f;
        for (int k = 0; k < FIN_; ++k) {
            const float tv = Tsum[row * WT_ + k];
            const u16* wp = &Wl[k * F_ + n0];
#pragma unroll
            for (int nn = 0; nn < 8; ++nn) u[nn] += tv * bf2f(wp[nn]);
        }
        float4_ o0, o1;
#pragma unroll
        for (int nn = 0; nn < 8; ++nn) {
            float hp = u[nn] * rden;
            float o  = hp > 0.f ? hp : expm1f(hp);
            if (nn < 4) o0[nn] = o; else o1[nn - 4] = o;
        }
        float* op = out + ((size_t)(b * M_ + i0 + row)) * F_ + n0;
        *(float4_*)op       = o0;
        *(float4_*)(op + 4) = o1;
    }
}

// ---------------------------------------------------------------------------
extern "C" void kernel_launch(void* const* d_in, const int* in_sizes, int n_in,
                              void* d_out, int out_size, void* d_ws, size_t ws_size,
                              hipStream_t stream)
{
    (void)out_size; (void)d_ws; (void)ws_size;
    const float* h  = (const float*)d_in[0];
    const int* adjp = (const int*)d_in[1];
    const float* Wp = (const float*)d_in[2];
    const float* ap = (const float*)d_in[3];
    for (int i = 0; i < n_in; ++i) {
        long s = in_sizes[i];
        if      (s == 4194304L)  h    = (const float*)d_in[i];
        else if (s == 67108864L) adjp = (const int*)d_in[i];
        else if (s == 8192L)     Wp   = (const float*)d_in[i];
        else if (s == 128L)      ap   = (const float*)d_in[i];
    }
    k_gat2<<<1024, 256, 0, stream>>>(h, adjp, Wp, ap, (float*)d_out);
}